// Round 1
// baseline (2469.612 us; speedup 1.0000x reference)
//
#include <hip/hip_runtime.h>
#include <math.h>

#define BG 8
#define NN 20000
#define EE 320000
#define CC 128
#define DD 64
#define NHOPS 4
#define HID 512
#define OUTD 256

// ---------------- small prep kernels ----------------

__global__ __launch_bounds__(256) void zero_kernel(int* __restrict__ p, int n) {
    int i = blockIdx.x * 256 + threadIdx.x;
    if (i < n) p[i] = 0;
}

// idx[n] = argmax_c P[c][n]  (first max wins, matches np.argmax)
__global__ __launch_bounds__(256) void argmax_kernel(const float* __restrict__ P, int* __restrict__ idx) {
    int n = blockIdx.x * 256 + threadIdx.x;
    if (n >= NN) return;
    float best = P[n];
    int bi = 0;
    #pragma unroll 4
    for (int c = 1; c < CC; ++c) {
        float v = P[c * NN + n];
        if (v > best) { best = v; bi = c; }
    }
    idx[n] = bi;
}

// init_emb[n][d] = emb[idx[n]][d]
__global__ __launch_bounds__(256) void gather_kernel(const int* __restrict__ idx, const float* __restrict__ emb,
                                                     float* __restrict__ init_emb) {
    int i = blockIdx.x * 256 + threadIdx.x;  // < NN*DD
    int n = i >> 6, d = i & 63;
    init_emb[i] = emb[idx[n] * DD + d];
}

// histogram of row indices per graph
__global__ __launch_bounds__(256) void hist_kernel(const int* __restrict__ ei, int* __restrict__ counts) {
    int i = blockIdx.x * 256 + threadIdx.x;  // < BG*EE
    int b = i / EE, e = i - b * EE;
    int row = ei[(long)b * 2 * EE + e];
    atomicAdd(&counts[b * NN + row], 1);
}

// per-graph exclusive scan of counts -> row_ptr (N+1) and cursor copy
__global__ __launch_bounds__(256) void scan_kernel(const int* __restrict__ counts, int* __restrict__ row_ptr,
                                                   int* __restrict__ cursor) {
    const int b = blockIdx.x, t = threadIdx.x;
    const int CH = (NN + 255) / 256;  // 79
    const int* cnt = counts + b * NN;
    int s0 = t * CH, s1 = min(s0 + CH, NN);
    int sum = 0;
    for (int i = s0; i < s1; ++i) sum += cnt[i];
    __shared__ int ss[256];
    ss[t] = sum;
    __syncthreads();
    for (int off = 1; off < 256; off <<= 1) {
        int v = (t >= off) ? ss[t - off] : 0;
        __syncthreads();
        ss[t] += v;
        __syncthreads();
    }
    int run = ss[t] - sum;  // exclusive prefix
    int* rp = row_ptr + b * (NN + 1);
    int* cur = cursor + b * NN;
    for (int i = s0; i < s1; ++i) {
        rp[i] = run;
        cur[i] = run;
        run += cnt[i];
    }
    if (t == 255) rp[NN] = ss[255];
}

// counting-sort scatter: col_sorted grouped by row
__global__ __launch_bounds__(256) void scatter_kernel(const int* __restrict__ ei, int* __restrict__ cursor,
                                                      int* __restrict__ col_sorted) {
    int i = blockIdx.x * 256 + threadIdx.x;  // < BG*EE
    int b = i / EE, e = i - b * EE;
    const int* eb = ei + (long)b * 2 * EE;
    int row = eb[e], col = eb[EE + e];
    int pos = atomicAdd(&cursor[b * NN + row], 1);
    col_sorted[(long)b * EE + pos] = col;
}

// ---------------- SPMM: one wave per node, lane = d ----------------
__global__ __launch_bounds__(256) void spmm_kernel(const float* __restrict__ Hin, int bstride,
                                                   const int* __restrict__ row_ptr,
                                                   const int* __restrict__ col_sorted, float* __restrict__ Hout) {
    int wave = threadIdx.x >> 6, lane = threadIdx.x & 63;
    int g = blockIdx.x * 4 + wave;  // global node id in [0, BG*NN)
    int b = g / NN, n = g - b * NN;
    const int* rp = row_ptr + b * (NN + 1);
    int s = rp[n], e = rp[n + 1];
    const float* hb = Hin + (long)b * bstride;
    const int* cs = col_sorted + (long)b * EE;
    float sum = 0.f;
    #pragma unroll 4
    for (int j = s; j < e; ++j) {
        int col = cs[j];  // wave-uniform
        sum += hb[(long)col * DD + lane];
    }
    Hout[(long)g * DD + lane] = sum;
}

// ---------------- fused MLP: GEMM1 + bias + LN + GELU + GEMM2 + bias ----------------
// 32 rows per block, 256 threads. LDS union: omega[32][256] then xact[32][512] (64 KB).
__global__ __launch_bounds__(256, 2) void mlp_kernel(const float* __restrict__ H,  // [hop][b][n][d]
                                                     const float* __restrict__ W1, const float* __restrict__ b1,
                                                     const float* __restrict__ gamma, const float* __restrict__ beta,
                                                     const float* __restrict__ W2, const float* __restrict__ b2,
                                                     float* __restrict__ out) {
    __shared__ float lds[32 * HID];  // 64 KB, exactly at static limit -> 2 blocks/CU
    const int t = threadIdx.x;
    const long g0 = (long)blockIdx.x * 32;
    const int b = (int)(g0 / NN);
    const int n0 = (int)(g0 - (long)b * NN);

    // stage omega[r][k] with k = d*4 + h; thread t owns k = t for all 32 rows.
    {
        const int d = t >> 2, h = t & 3;
        const float* src = H + (((long)h * BG + b) * NN + n0) * DD + d;
        #pragma unroll
        for (int r = 0; r < 32; ++r) lds[r * 256 + t] = src[(long)r * DD];
    }
    __syncthreads();

    // GEMM1: x[r][c] = sum_k omega[r][k] * W1[k][c]; thread t -> cols {2t, 2t+1}
    float2 acc[32];
    #pragma unroll
    for (int r = 0; r < 32; ++r) { acc[r].x = 0.f; acc[r].y = 0.f; }
    for (int k4 = 0; k4 < 256; k4 += 4) {
        float2 wa = *(const float2*)(W1 + (k4 + 0) * HID + 2 * t);
        float2 wb = *(const float2*)(W1 + (k4 + 1) * HID + 2 * t);
        float2 wc = *(const float2*)(W1 + (k4 + 2) * HID + 2 * t);
        float2 wd = *(const float2*)(W1 + (k4 + 3) * HID + 2 * t);
        #pragma unroll
        for (int r = 0; r < 32; ++r) {
            float4 ov = *(const float4*)(lds + r * 256 + k4);  // wave-uniform broadcast
            acc[r].x += ov.x * wa.x + ov.y * wb.x + ov.z * wc.x + ov.w * wd.x;
            acc[r].y += ov.x * wa.y + ov.y * wb.y + ov.z * wc.y + ov.w * wd.y;
        }
    }
    __syncthreads();  // everyone done reading omega before overwrite

    {
        float2 bb = *(const float2*)(b1 + 2 * t);
        #pragma unroll
        for (int r = 0; r < 32; ++r) {
            float2 v;
            v.x = acc[r].x + bb.x;
            v.y = acc[r].y + bb.y;
            *(float2*)(lds + r * HID + 2 * t) = v;
        }
    }
    __syncthreads();

    // LayerNorm + exact GELU; one wave handles 8 rows
    {
        const int wave = t >> 6, lane = t & 63;
        float gam[8], bet[8];
        #pragma unroll
        for (int i = 0; i < 8; ++i) {
            gam[i] = gamma[i * 64 + lane];
            bet[i] = beta[i * 64 + lane];
        }
        for (int rr = 0; rr < 8; ++rr) {
            int r = wave * 8 + rr;
            float v[8];
            float s1 = 0.f, s2 = 0.f;
            #pragma unroll
            for (int i = 0; i < 8; ++i) {
                v[i] = lds[r * HID + i * 64 + lane];
                s1 += v[i];
                s2 += v[i] * v[i];
            }
            #pragma unroll
            for (int off = 32; off > 0; off >>= 1) {
                s1 += __shfl_down(s1, off, 64);
                s2 += __shfl_down(s2, off, 64);
            }
            s1 = __shfl(s1, 0, 64);
            s2 = __shfl(s2, 0, 64);
            float mean = s1 * (1.f / HID);
            float var = s2 * (1.f / HID) - mean * mean;
            float rstd = rsqrtf(var + 1e-5f);
            #pragma unroll
            for (int i = 0; i < 8; ++i) {
                float x = (v[i] - mean) * rstd * gam[i] + bet[i];
                float gl = 0.5f * x * (1.f + erff(x * 0.70710678118654752f));
                lds[r * HID + i * 64 + lane] = gl;
            }
        }
    }
    __syncthreads();

    // GEMM2: out[r][o] = sum_c xact[r][c] * W2[c][o]; thread t -> col o = t
    float acc2[32];
    #pragma unroll
    for (int r = 0; r < 32; ++r) acc2[r] = 0.f;
    for (int c4 = 0; c4 < HID; c4 += 4) {
        float wa = W2[(c4 + 0) * OUTD + t];
        float wb = W2[(c4 + 1) * OUTD + t];
        float wc = W2[(c4 + 2) * OUTD + t];
        float wd = W2[(c4 + 3) * OUTD + t];
        #pragma unroll
        for (int r = 0; r < 32; ++r) {
            float4 xv = *(const float4*)(lds + r * HID + c4);  // wave-uniform broadcast
            acc2[r] += xv.x * wa + xv.y * wb + xv.z * wc + xv.w * wd;
        }
    }
    float bo = b2[t];
    #pragma unroll
    for (int r = 0; r < 32; ++r) out[(g0 + r) * OUTD + t] = acc2[r] + bo;
}

// ---------------- launch ----------------

extern "C" void kernel_launch(void* const* d_in, const int* in_sizes, int n_in, void* d_out, int out_size,
                              void* d_ws, size_t ws_size, hipStream_t stream) {
    const int* ei = (const int*)d_in[0];       // (B,2,E) int32
    const float* P = (const float*)d_in[2];    // (C,N)
    const float* emb = (const float*)d_in[3];  // (C,D)
    const float* W1 = (const float*)d_in[4];   // (256,512)
    const float* b1 = (const float*)d_in[5];
    const float* gamma = (const float*)d_in[6];
    const float* beta = (const float*)d_in[7];
    const float* W2 = (const float*)d_in[8];  // (512,256)
    const float* b2 = (const float*)d_in[9];
    float* out = (float*)d_out;

    char* ws = (char*)d_ws;
    size_t off = 0;
    auto alloc = [&](size_t bytes) -> char* {
        char* p = ws + off;
        off += (bytes + 1023) & ~(size_t)1023;
        return p;
    };
    int* idx = (int*)alloc((size_t)NN * 4);
    float* init_emb = (float*)alloc((size_t)NN * DD * 4);
    int* counts = (int*)alloc((size_t)BG * NN * 4);
    int* row_ptr = (int*)alloc((size_t)BG * (NN + 1) * 4);
    int* cursor = (int*)alloc((size_t)BG * NN * 4);
    int* col_sorted = (int*)alloc((size_t)BG * EE * 4);
    float* H = (float*)alloc((size_t)NHOPS * BG * NN * DD * 4);  // total ws ~182 MB

    hipLaunchKernelGGL(zero_kernel, dim3((BG * NN + 255) / 256), dim3(256), 0, stream, counts, BG * NN);
    hipLaunchKernelGGL(argmax_kernel, dim3((NN + 255) / 256), dim3(256), 0, stream, P, idx);
    hipLaunchKernelGGL(gather_kernel, dim3(NN * DD / 256), dim3(256), 0, stream, idx, emb, init_emb);
    hipLaunchKernelGGL(hist_kernel, dim3(BG * EE / 256), dim3(256), 0, stream, ei, counts);
    hipLaunchKernelGGL(scan_kernel, dim3(BG), dim3(256), 0, stream, counts, row_ptr, cursor);
    hipLaunchKernelGGL(scatter_kernel, dim3(BG * EE / 256), dim3(256), 0, stream, ei, cursor, col_sorted);

    const long hs = (long)BG * NN * DD;
    for (int h = 0; h < NHOPS; ++h) {
        const float* hin = (h == 0) ? init_emb : (H + (long)(h - 1) * hs);
        int bstride = (h == 0) ? 0 : NN * DD;
        hipLaunchKernelGGL(spmm_kernel, dim3(BG * NN / 4), dim3(256), 0, stream, hin, bstride, row_ptr, col_sorted,
                           H + (long)h * hs);
    }
    hipLaunchKernelGGL(mlp_kernel, dim3(BG * NN / 32), dim3(256), 0, stream, H, W1, b1, gamma, beta, W2, b2, out);
}

// Round 4
// 1136.296 us; speedup vs baseline: 2.1734x; 2.1734x over previous
//
#include <hip/hip_runtime.h>
#include <math.h>

#define BG 8
#define NN 20000
#define EE 320000
#define CC 128
#define DD 64
#define NHOPS 4
#define HID 512
#define OUTD 256

typedef __attribute__((ext_vector_type(8))) short short8;
typedef __attribute__((ext_vector_type(4))) float f32x4;

__device__ __forceinline__ unsigned short f2bf(float f) {
    unsigned u = __float_as_uint(f);
    u += 0x7fffu + ((u >> 16) & 1u);  // RNE
    return (unsigned short)(u >> 16);
}

// LDS lane swizzle: spread epilogue-repack writes across banks.
// bit0 ^= bit4, bit1 ^= bit3. Involution => bijection.
__device__ __forceinline__ int swz(int la) {
    return la ^ ((la >> 4) & 1) ^ (((la >> 3) & 1) << 1);
}

// ---------------- small prep kernels ----------------

__global__ __launch_bounds__(256) void zero_kernel(int* __restrict__ p, int n) {
    int i = blockIdx.x * 256 + threadIdx.x;
    if (i < n) p[i] = 0;
}

__global__ __launch_bounds__(256) void argmax_kernel(const float* __restrict__ P, int* __restrict__ idx) {
    int n = blockIdx.x * 256 + threadIdx.x;
    if (n >= NN) return;
    float best = P[n];
    int bi = 0;
    #pragma unroll 4
    for (int c = 1; c < CC; ++c) {
        float v = P[c * NN + n];
        if (v > best) { best = v; bi = c; }
    }
    idx[n] = bi;
}

__global__ __launch_bounds__(256) void gather_kernel(const int* __restrict__ idx, const float* __restrict__ emb,
                                                     float* __restrict__ init_emb) {
    int i = blockIdx.x * 256 + threadIdx.x;
    int n = i >> 6, d = i & 63;
    init_emb[i] = emb[idx[n] * DD + d];
}

__global__ __launch_bounds__(256) void hist_kernel(const int* __restrict__ ei, int* __restrict__ counts) {
    int i = blockIdx.x * 256 + threadIdx.x;
    int b = i / EE, e = i - b * EE;
    int row = ei[(long)b * 2 * EE + e];
    atomicAdd(&counts[b * NN + row], 1);
}

__global__ __launch_bounds__(256) void scan_kernel(const int* __restrict__ counts, int* __restrict__ row_ptr,
                                                   int* __restrict__ cursor) {
    const int b = blockIdx.x, t = threadIdx.x;
    const int CH = (NN + 255) / 256;
    const int* cnt = counts + b * NN;
    int s0 = t * CH, s1 = min(s0 + CH, NN);
    int sum = 0;
    for (int i = s0; i < s1; ++i) sum += cnt[i];
    __shared__ int ss[256];
    ss[t] = sum;
    __syncthreads();
    for (int off = 1; off < 256; off <<= 1) {
        int v = (t >= off) ? ss[t - off] : 0;
        __syncthreads();
        ss[t] += v;
        __syncthreads();
    }
    int run = ss[t] - sum;
    int* rp = row_ptr + b * (NN + 1);
    int* cur = cursor + b * NN;
    for (int i = s0; i < s1; ++i) {
        rp[i] = run;
        cur[i] = run;
        run += cnt[i];
    }
    if (t == 255) rp[NN] = ss[255];
}

__global__ __launch_bounds__(256) void scatter_kernel(const int* __restrict__ ei, int* __restrict__ cursor,
                                                      int* __restrict__ col_sorted) {
    int i = blockIdx.x * 256 + threadIdx.x;
    int b = i / EE, e = i - b * EE;
    const int* eb = ei + (long)b * 2 * EE;
    int row = eb[e], col = eb[EE + e];
    int pos = atomicAdd(&cursor[b * NN + row], 1);
    col_sorted[(long)b * EE + pos] = col;
}

// ---------------- SPMM: one wave per node, lane = d ----------------
__global__ __launch_bounds__(256) void spmm_kernel(const float* __restrict__ Hin, int bstride,
                                                   const int* __restrict__ row_ptr,
                                                   const int* __restrict__ col_sorted, float* __restrict__ Hout) {
    int wave = threadIdx.x >> 6, lane = threadIdx.x & 63;
    int g = blockIdx.x * 4 + wave;
    int b = g / NN, n = g - b * NN;
    const int* rp = row_ptr + b * (NN + 1);
    int s = rp[n], e = rp[n + 1];
    const float* hb = Hin + (long)b * bstride;
    const int* cs = col_sorted + (long)b * EE;
    float sum = 0.f;
    #pragma unroll 4
    for (int j = s; j < e; ++j) {
        int col = cs[j];
        sum += hb[(long)col * DD + lane];
    }
    Hout[(long)g * DD + lane] = sum;
}

// ---------------- weight packing: bf16 B-fragment layout ----------------
// W1 packed: i = ((ct*8+kb)*64+la)*8+j, element = W1[kb*32+(la>>4)*8+j][ct*16+(la&15)]
__global__ __launch_bounds__(256) void pack_w1_kernel(const float* __restrict__ W1, short* __restrict__ w1p) {
    int i = blockIdx.x * 256 + threadIdx.x;  // < 131072
    int j = i & 7, la = (i >> 3) & 63, kb = (i >> 9) & 7, ct = i >> 12;
    int k = kb * 32 + ((la >> 4) & 3) * 8 + j;
    int col = ct * 16 + (la & 15);
    w1p[i] = (short)f2bf(W1[k * HID + col]);
}

// W2 packed: i = ((ct*16+kb)*64+la)*8+j
__global__ __launch_bounds__(256) void pack_w2_kernel(const float* __restrict__ W2, short* __restrict__ w2p) {
    int i = blockIdx.x * 256 + threadIdx.x;  // < 131072
    int j = i & 7, la = (i >> 3) & 63, kb = (i >> 9) & 15, ct = i >> 13;
    int k = kb * 32 + ((la >> 4) & 3) * 8 + j;
    int col = ct * 16 + (la & 15);
    w2p[i] = (short)f2bf(W2[k * OUTD + col]);
}

// ---------------- fused MFMA MLP ----------------
// 64 rows/block, 256 threads (4 waves). Wave w: GEMM1 cols [w*128,w*128+128), GEMM2 cols [w*64,w*64+64).
// One 64 KB LDS buffer reused: omega-frags (32 KB) -> LN partials (2 KB) -> xact-frags (64 KB).
__global__ __launch_bounds__(256, 2) void mlp_mfma_kernel(const float* __restrict__ H,  // [hop][b][n][d]
                                                          const short* __restrict__ w1p,
                                                          const float* __restrict__ b1,
                                                          const float* __restrict__ gamma,
                                                          const float* __restrict__ beta,
                                                          const short* __restrict__ w2p,
                                                          const float* __restrict__ b2, float* __restrict__ out) {
    __shared__ short buf[32768];  // 64 KB
    const int t = threadIdx.x;
    const int w = t >> 6, l = t & 63;
    const int q = l >> 4, cl = l & 15;
    const int lF = swz(l);
    const long g0 = (long)blockIdx.x * 64;

    // ---- Phase 1: stage omega[64][256] as bf16 A-fragments; k = d*4 + h = t ----
    {
        const int h = t & 3, d = t >> 2;
        const float* src = H + ((long)h * (BG * NN) + g0) * DD + d;
        const int kb = t >> 5, quad = (t >> 3) & 3, j = t & 7;
        #pragma unroll 8
        for (int r = 0; r < 64; ++r) {
            unsigned short v = f2bf(src[(long)r * DD]);
            int rt = r >> 4;
            int la = swz((r & 15) | (quad << 4));
            buf[((rt * 8 + kb) * 64 + la) * 8 + j] = (short)v;
        }
    }
    __syncthreads();

    // ---- Phase 2: GEMM1: acc[rt][c] = omega(64x256) @ W1(256x512) wave-slice ----
    f32x4 acc[4][8];
    #pragma unroll
    for (int rt = 0; rt < 4; ++rt)
        #pragma unroll
        for (int c = 0; c < 8; ++c) acc[rt][c] = (f32x4)(0.f);
    #pragma unroll 2
    for (int kb = 0; kb < 8; ++kb) {
        short8 a[4];
        #pragma unroll
        for (int rt = 0; rt < 4; ++rt) a[rt] = *(const short8*)&buf[((rt * 8 + kb) * 64 + lF) * 8];
        #pragma unroll
        for (int c = 0; c < 8; ++c) {
            const short8 bfr = *(const short8*)(w1p + (((size_t)(w * 8 + c) * 8 + kb) * 64 + l) * 8);
            #pragma unroll
            for (int rt = 0; rt < 4; ++rt)
                acc[rt][c] = __builtin_amdgcn_mfma_f32_16x16x32_bf16(a[rt], bfr, acc[rt][c], 0, 0, 0);
        }
    }
    __syncthreads();  // done reading omega

    // ---- Phase 3: bias + row partial sums -> LDS ----
    float b1v[8], gv[8], bv[8];
    #pragma unroll
    for (int c = 0; c < 8; ++c) {
        int col = (w * 8 + c) * 16 + cl;
        b1v[c] = b1[col];
        gv[c] = gamma[col];
        bv[c] = beta[col];
    }
    float s1[4][4], s2[4][4];
    #pragma unroll
    for (int rt = 0; rt < 4; ++rt)
        #pragma unroll
        for (int i = 0; i < 4; ++i) {
            float a = 0.f, bb = 0.f;
            #pragma unroll
            for (int c = 0; c < 8; ++c) {
                float x = acc[rt][c][i] + b1v[c];
                acc[rt][c][i] = x;
                a += x;
                bb += x * x;
            }
            s1[rt][i] = a;
            s2[rt][i] = bb;
        }
    #pragma unroll
    for (int m = 1; m < 16; m <<= 1)
        #pragma unroll
        for (int rt = 0; rt < 4; ++rt)
            #pragma unroll
            for (int i = 0; i < 4; ++i) {
                s1[rt][i] += __shfl_xor(s1[rt][i], m, 64);
                s2[rt][i] += __shfl_xor(s2[rt][i], m, 64);
            }
    float* s1a = (float*)buf;        // [64][4]
    float* s2a = (float*)buf + 256;  // [64][4]
    if (cl == 0) {
        #pragma unroll
        for (int rt = 0; rt < 4; ++rt)
            #pragma unroll
            for (int i = 0; i < 4; ++i) {
                int row = rt * 16 + q * 4 + i;
                s1a[row * 4 + w] = s1[rt][i];
                s2a[row * 4 + w] = s2[rt][i];
            }
    }
    __syncthreads();

    // ---- Phase 4: finalize mean/rstd ----
    float mean[4][4], rstd[4][4];
    #pragma unroll
    for (int rt = 0; rt < 4; ++rt)
        #pragma unroll
        for (int i = 0; i < 4; ++i) {
            int row = rt * 16 + q * 4 + i;
            float a = s1a[row * 4] + s1a[row * 4 + 1] + s1a[row * 4 + 2] + s1a[row * 4 + 3];
            float bb = s2a[row * 4] + s2a[row * 4 + 1] + s2a[row * 4 + 2] + s2a[row * 4 + 3];
            float mu = a * (1.f / HID);
            float var = bb * (1.f / HID) - mu * mu;
            mean[rt][i] = mu;
            rstd[rt][i] = rsqrtf(var + 1e-5f);
        }
    __syncthreads();  // LN reads done before xact overwrites

    // ---- Phase 5: LN + GELU + repack as bf16 A-fragments (xact[64][512]) ----
    #pragma unroll
    for (int rt = 0; rt < 4; ++rt)
        #pragma unroll
        for (int c = 0; c < 8; ++c) {
            int col = (w * 8 + c) * 16 + cl;
            int kb2 = col >> 5, quad2 = (col >> 3) & 3, j2 = col & 7;
            #pragma unroll
            for (int i = 0; i < 4; ++i) {
                float x = (acc[rt][c][i] - mean[rt][i]) * rstd[rt][i] * gv[c] + bv[c];
                float g = 0.5f * x * (1.f + erff(x * 0.70710678118654752f));
                int la = swz((q * 4 + i) | (quad2 << 4));
                buf[((rt * 16 + kb2) * 64 + la) * 8 + j2] = (short)f2bf(g);
            }
        }
    __syncthreads();

    // ---- Phase 6: GEMM2: out-slice = xact(64x512) @ W2(512x256) ----
    f32x4 acc2[4][4];
    #pragma unroll
    for (int rt = 0; rt < 4; ++rt)
        #pragma unroll
        for (int c = 0; c < 4; ++c) acc2[rt][c] = (f32x4)(0.f);
    #pragma unroll 2
    for (int kb = 0; kb < 16; ++kb) {
        short8 a[4];
        #pragma unroll
        for (int rt = 0; rt < 4; ++rt) a[rt] = *(const short8*)&buf[((rt * 16 + kb) * 64 + lF) * 8];
        #pragma unroll
        for (int c = 0; c < 4; ++c) {
            const short8 bfr = *(const short8*)(w2p + (((size_t)(w * 4 + c) * 16 + kb) * 64 + l) * 8);
            #pragma unroll
            for (int rt = 0; rt < 4; ++rt)
                acc2[rt][c] = __builtin_amdgcn_mfma_f32_16x16x32_bf16(a[rt], bfr, acc2[rt][c], 0, 0, 0);
        }
    }

    // ---- Phase 7: bias + store ----
    float b2v[4];
    #pragma unroll
    for (int c = 0; c < 4; ++c) b2v[c] = b2[(w * 4 + c) * 16 + cl];
    #pragma unroll
    for (int rt = 0; rt < 4; ++rt)
        #pragma unroll
        for (int c = 0; c < 4; ++c)
            #pragma unroll
            for (int i = 0; i < 4; ++i) {
                long g = g0 + rt * 16 + q * 4 + i;
                out[g * OUTD + (w * 4 + c) * 16 + cl] = acc2[rt][c][i] + b2v[c];
            }
}

// ---------------- launch ----------------

extern "C" void kernel_launch(void* const* d_in, const int* in_sizes, int n_in, void* d_out, int out_size,
                              void* d_ws, size_t ws_size, hipStream_t stream) {
    const int* ei = (const int*)d_in[0];
    const float* P = (const float*)d_in[2];
    const float* emb = (const float*)d_in[3];
    const float* W1 = (const float*)d_in[4];
    const float* b1 = (const float*)d_in[5];
    const float* gamma = (const float*)d_in[6];
    const float* beta = (const float*)d_in[7];
    const float* W2 = (const float*)d_in[8];
    const float* b2 = (const float*)d_in[9];
    float* out = (float*)d_out;

    char* ws = (char*)d_ws;
    size_t off = 0;
    auto alloc = [&](size_t bytes) -> char* {
        char* p = ws + off;
        off += (bytes + 1023) & ~(size_t)1023;
        return p;
    };
    int* idx = (int*)alloc((size_t)NN * 4);
    float* init_emb = (float*)alloc((size_t)NN * DD * 4);
    int* counts = (int*)alloc((size_t)BG * NN * 4);
    int* row_ptr = (int*)alloc((size_t)BG * (NN + 1) * 4);
    int* cursor = (int*)alloc((size_t)BG * NN * 4);
    int* col_sorted = (int*)alloc((size_t)BG * EE * 4);
    short* w1p = (short*)alloc((size_t)131072 * 2);
    short* w2p = (short*)alloc((size_t)131072 * 2);
    float* H = (float*)alloc((size_t)NHOPS * BG * NN * DD * 4);

    hipLaunchKernelGGL(zero_kernel, dim3((BG * NN + 255) / 256), dim3(256), 0, stream, counts, BG * NN);
    hipLaunchKernelGGL(argmax_kernel, dim3((NN + 255) / 256), dim3(256), 0, stream, P, idx);
    hipLaunchKernelGGL(gather_kernel, dim3(NN * DD / 256), dim3(256), 0, stream, idx, emb, init_emb);
    hipLaunchKernelGGL(hist_kernel, dim3(BG * EE / 256), dim3(256), 0, stream, ei, counts);
    hipLaunchKernelGGL(scan_kernel, dim3(BG), dim3(256), 0, stream, counts, row_ptr, cursor);
    hipLaunchKernelGGL(scatter_kernel, dim3(BG * EE / 256), dim3(256), 0, stream, ei, cursor, col_sorted);
    hipLaunchKernelGGL(pack_w1_kernel, dim3(512), dim3(256), 0, stream, W1, w1p);
    hipLaunchKernelGGL(pack_w2_kernel, dim3(512), dim3(256), 0, stream, W2, w2p);

    const long hs = (long)BG * NN * DD;
    for (int h = 0; h < NHOPS; ++h) {
        const float* hin = (h == 0) ? init_emb : (H + (long)(h - 1) * hs);
        int bstride = (h == 0) ? 0 : NN * DD;
        hipLaunchKernelGGL(spmm_kernel, dim3(BG * NN / 4), dim3(256), 0, stream, hin, bstride, row_ptr, col_sorted,
                           H + (long)h * hs);
    }
    hipLaunchKernelGGL(mlp_mfma_kernel, dim3(BG * NN / 64), dim3(256), 0, stream, H, w1p, b1, gamma, beta, w2p, b2,
                       out);
}